// Round 3
// baseline (134.689 us; speedup 1.0000x reference)
//
#include <hip/hip_runtime.h>

#define N_ELEMS_C 400000
#define N_NODES_C 200000
#define STATE_N   3200000   // N_ELEMS * NQ * 1

// Kernel A: repack us [N_NODES][3] (12B records, splits cache lines when
// gathered) into d_ws as [N_NODES] float4 (16B aligned, single-line gathers).
// Fully coalesced: each thread handles 4 nodes = 3 float4 reads, 4 float4 writes.
// 200000 = 4*50000 exactly; 600000 floats = 150000 float4 exactly.
__global__ __launch_bounds__(256) void repack_us_kernel(
    const float* __restrict__ us, float4* __restrict__ usw)
{
    const int t = blockIdx.x * 256 + threadIdx.x;   // node group [0, 50000)
    if (t < N_NODES_C / 4) {
        const float4* src = reinterpret_cast<const float4*>(us);
        const float4 a = src[3 * t + 0];
        const float4 b = src[3 * t + 1];
        const float4 c = src[3 * t + 2];
        usw[4 * t + 0] = make_float4(a.x, a.y, a.z, 0.f);
        usw[4 * t + 1] = make_float4(a.w, b.x, b.y, 0.f);
        usw[4 * t + 2] = make_float4(b.z, b.w, c.x, 0.f);
        usw[4 * t + 3] = make_float4(c.y, c.z, c.w, 0.f);
    }
}

// Kernel B: fused state passthrough + neo-Hookean energy.
// Gathers are now one global_load_dwordx4 per node (8 per thread, was 24
// scalar dwords) — the gather was the latency bottleneck (R2: 1 TB/s
// effective, VALUBusy 20%).
__global__ __launch_bounds__(256) void fused_energy_kernel(
    const float* __restrict__ params,
    const float4* __restrict__ usw,        // repacked [N_NODES] float4
    const float* __restrict__ shape_grads, // [8][8][3]
    const float* __restrict__ jxws,        // [E][8]
    const int*   __restrict__ conns,       // [E][8]
    const float* __restrict__ state_old,   // [E*8]
    float* __restrict__ out)               // [1 + E*8]
{
    __shared__ float s_sg[192];
    __shared__ float s_wsum[4];
    const int tid = threadIdx.x;
    const int b   = blockIdx.x;
    if (tid < 192) s_sg[tid] = shape_grads[tid];

    // ---- state passthrough (independent of s_sg) ----
    {
        const int base4 = b * 512;
        #pragma unroll
        for (int k = 0; k < 2; ++k) {
            const int i4 = base4 + k * 256 + tid;
            if (i4 < STATE_N / 4) {
                const float4 v = reinterpret_cast<const float4*>(state_old)[i4];
                const int i = i4 * 4;
                out[1 + i + 0] = v.x;
                out[1 + i + 1] = v.y;
                out[1 + i + 2] = v.z;
                out[1 + i + 3] = v.w;
            }
        }
    }

    __syncthreads();   // s_sg ready

    const int e = b * 256 + tid;
    float acc = 0.0f;
    if (e < N_ELEMS_C) {
        const float mu  = params[0];
        const float lam = params[1];

        const int4 c0 = reinterpret_cast<const int4*>(conns)[2 * e + 0];
        const int4 c1 = reinterpret_cast<const int4*>(conns)[2 * e + 1];
        const int ci[8] = {c0.x, c0.y, c0.z, c0.w, c1.x, c1.y, c1.z, c1.w};

        // 8 independent 16B gathers, L2-resident (3.2 MB), never line-split
        float4 uv[8];
        #pragma unroll
        for (int n = 0; n < 8; ++n) uv[n] = usw[ci[n]];

        const float4 j0 = reinterpret_cast<const float4*>(jxws)[2 * e + 0];
        const float4 j1 = reinterpret_cast<const float4*>(jxws)[2 * e + 1];
        const float jq[8] = {j0.x, j0.y, j0.z, j0.w, j1.x, j1.y, j1.z, j1.w};

        #pragma unroll
        for (int q = 0; q < 8; ++q) {
            // grad_uq[f][d] = sum_n shape_grads[q][n][d] * uv[n][f]
            float g00=0.f,g01=0.f,g02=0.f,g10=0.f,g11=0.f,g12=0.f,g20=0.f,g21=0.f,g22=0.f;
            #pragma unroll
            for (int n = 0; n < 8; ++n) {
                const float d0 = s_sg[(q * 8 + n) * 3 + 0];  // broadcast LDS reads
                const float d1 = s_sg[(q * 8 + n) * 3 + 1];
                const float d2 = s_sg[(q * 8 + n) * 3 + 2];
                const float u0 = uv[n].x, u1 = uv[n].y, u2 = uv[n].z;
                g00 = fmaf(d0, u0, g00); g01 = fmaf(d1, u0, g01); g02 = fmaf(d2, u0, g02);
                g10 = fmaf(d0, u1, g10); g11 = fmaf(d1, u1, g11); g12 = fmaf(d2, u1, g12);
                g20 = fmaf(d0, u2, g20); g21 = fmaf(d1, u2, g21); g22 = fmaf(d2, u2, g22);
            }
            const float F00 = g00 + 1.0f, F01 = g01,        F02 = g02;
            const float F10 = g10,        F11 = g11 + 1.0f, F12 = g12;
            const float F20 = g20,        F21 = g21,        F22 = g22 + 1.0f;

            const float det = F00 * (F11 * F22 - F12 * F21)
                            - F01 * (F10 * F22 - F12 * F20)
                            + F02 * (F10 * F21 - F11 * F20);
            const float I1 = F00*F00 + F01*F01 + F02*F02
                           + F10*F10 + F11*F11 + F12*F12
                           + F20*F20 + F21*F21 + F22*F22;
            const float lj = __logf(det);
            const float fq = 0.5f * mu * (I1 - 3.0f - 2.0f * lj)
                           + 0.5f * lam * lj * lj;
            acc = fmaf(jq[q], fq, acc);
        }
    }

    // wave-64 shuffle reduce -> per-block LDS reduce -> one atomic per block
    #pragma unroll
    for (int off = 32; off > 0; off >>= 1)
        acc += __shfl_down(acc, off, 64);
    const int lane = tid & 63;
    const int wv   = tid >> 6;
    if (lane == 0) s_wsum[wv] = acc;
    __syncthreads();
    if (tid == 0) {
        atomicAdd(out, s_wsum[0] + s_wsum[1] + s_wsum[2] + s_wsum[3]);
    }
}

extern "C" void kernel_launch(void* const* d_in, const int* in_sizes, int n_in,
                              void* d_out, int out_size, void* d_ws, size_t ws_size,
                              hipStream_t stream) {
    const float* params      = (const float*)d_in[0];
    // d_in[1] coords, d_in[2] t, d_in[4] shape_vals, d_in[7] dt — dead inputs
    const float* us          = (const float*)d_in[3];
    const float* shape_grads = (const float*)d_in[5];
    const float* jxws        = (const float*)d_in[6];
    const float* state_old   = (const float*)d_in[8];
    const int*   conns       = (const int*)d_in[9];
    float* out   = (float*)d_out;
    float4* usw  = (float4*)d_ws;   // 3.2 MB of the 256 MB scratch

    hipLaunchKernelGGL(repack_us_kernel,
                       dim3((N_NODES_C / 4 + 255) / 256), dim3(256), 0, stream,
                       us, usw);
    hipLaunchKernelGGL(fused_energy_kernel,
                       dim3((N_ELEMS_C + 255) / 256), dim3(256), 0, stream,
                       params, usw, shape_grads, jxws, conns, state_old, out);
}

// Round 4
// 133.209 us; speedup vs baseline: 1.0111x; 1.0111x over previous
//
#include <hip/hip_runtime.h>

#define N_ELEMS_C 400000
#define N_NODES_C 200000
#define STATE_N   3200000   // N_ELEMS * NQ * 1

// Kernel A: repack us [N_NODES][3] (12B records, line-splitting when gathered)
// into d_ws as [N_NODES] float4 (16B aligned -> every gather is exactly one
// cache-line transaction). Fully coalesced; 200000 nodes = 150000 float4 reads.
__global__ __launch_bounds__(256) void repack_us_kernel(
    const float* __restrict__ us, float4* __restrict__ usw)
{
    const int t = blockIdx.x * 256 + threadIdx.x;   // node group [0, 50000)
    if (t < N_NODES_C / 4) {
        const float4* src = reinterpret_cast<const float4*>(us);
        const float4 a = src[3 * t + 0];
        const float4 b = src[3 * t + 1];
        const float4 c = src[3 * t + 2];
        usw[4 * t + 0] = make_float4(a.x, a.y, a.z, 0.f);
        usw[4 * t + 1] = make_float4(a.w, b.x, b.y, 0.f);
        usw[4 * t + 2] = make_float4(b.z, b.w, c.x, 0.f);
        usw[4 * t + 3] = make_float4(c.y, c.z, c.w, 0.f);
    }
}

// Kernel B: fused state passthrough + neo-Hookean energy.
// R3 pipe model said LDS was the tallest pipe (192 ds_read_b32/thread = 11.3
// us/CU). Fix: stage shape_grads TRANSPOSED as [q][d][n] so each (q,d) row is
// 8 contiguous floats -> 2 ds_read_b128; 48 b128 reads/thread (~5.8 us), below
// the 8.6 us HBM stream floor.
__global__ __launch_bounds__(256) void fused_energy_kernel(
    const float* __restrict__ params,
    const float4* __restrict__ usw,        // repacked [N_NODES] float4
    const float* __restrict__ shape_grads, // [8][8][3] = [q][n][d]
    const float* __restrict__ jxws,        // [E][8]
    const int*   __restrict__ conns,       // [E][8]
    const float* __restrict__ state_old,   // [E*8]
    float* __restrict__ out)               // [1 + E*8]
{
    __shared__ __align__(16) float s_sgT[192];  // [q][d][n] transposed
    __shared__ float s_wsum[4];
    const int tid = threadIdx.x;
    const int b   = blockIdx.x;

    if (tid < 192) {
        const int q = tid / 24;
        const int r = tid % 24;
        const int d = r / 8;
        const int n = r % 8;
        s_sgT[tid] = shape_grads[(q * 8 + n) * 3 + d];
    }

    // ---- state passthrough (independent of s_sgT) ----
    {
        const int base4 = b * 512;
        #pragma unroll
        for (int k = 0; k < 2; ++k) {
            const int i4 = base4 + k * 256 + tid;
            if (i4 < STATE_N / 4) {
                const float4 v = reinterpret_cast<const float4*>(state_old)[i4];
                const int i = i4 * 4;
                out[1 + i + 0] = v.x;
                out[1 + i + 1] = v.y;
                out[1 + i + 2] = v.z;
                out[1 + i + 3] = v.w;
            }
        }
    }

    __syncthreads();   // s_sgT ready

    const int e = b * 256 + tid;
    float acc = 0.0f;
    if (e < N_ELEMS_C) {
        const float mu  = params[0];
        const float lam = params[1];

        const int4 c0 = reinterpret_cast<const int4*>(conns)[2 * e + 0];
        const int4 c1 = reinterpret_cast<const int4*>(conns)[2 * e + 1];
        const int ci[8] = {c0.x, c0.y, c0.z, c0.w, c1.x, c1.y, c1.z, c1.w};

        // 8 independent 16B gathers, L2-resident (3.2 MB), never line-split
        float4 uv[8];
        #pragma unroll
        for (int n = 0; n < 8; ++n) uv[n] = usw[ci[n]];

        const float4 j0 = reinterpret_cast<const float4*>(jxws)[2 * e + 0];
        const float4 j1 = reinterpret_cast<const float4*>(jxws)[2 * e + 1];
        const float jq[8] = {j0.x, j0.y, j0.z, j0.w, j1.x, j1.y, j1.z, j1.w};

        #pragma unroll
        for (int q = 0; q < 8; ++q) {
            // 6 x ds_read_b128 (broadcast, conflict-free): all 24 shape-grad
            // values for this q
            const float4* sgq = reinterpret_cast<const float4*>(s_sgT + q * 24);
            const float4 A0 = sgq[0], A1 = sgq[1];   // d=0, n=0..7
            const float4 B0 = sgq[2], B1 = sgq[3];   // d=1
            const float4 C0 = sgq[4], C1 = sgq[5];   // d=2
            const float d0[8] = {A0.x, A0.y, A0.z, A0.w, A1.x, A1.y, A1.z, A1.w};
            const float d1[8] = {B0.x, B0.y, B0.z, B0.w, B1.x, B1.y, B1.z, B1.w};
            const float d2[8] = {C0.x, C0.y, C0.z, C0.w, C1.x, C1.y, C1.z, C1.w};

            // grad_uq[f][d] = sum_n shape_grads[q][n][d] * uv[n][f]
            float g00=0.f,g01=0.f,g02=0.f,g10=0.f,g11=0.f,g12=0.f,g20=0.f,g21=0.f,g22=0.f;
            #pragma unroll
            for (int n = 0; n < 8; ++n) {
                const float u0 = uv[n].x, u1 = uv[n].y, u2 = uv[n].z;
                g00 = fmaf(d0[n], u0, g00); g01 = fmaf(d1[n], u0, g01); g02 = fmaf(d2[n], u0, g02);
                g10 = fmaf(d0[n], u1, g10); g11 = fmaf(d1[n], u1, g11); g12 = fmaf(d2[n], u1, g12);
                g20 = fmaf(d0[n], u2, g20); g21 = fmaf(d1[n], u2, g21); g22 = fmaf(d2[n], u2, g22);
            }
            const float F00 = g00 + 1.0f, F01 = g01,        F02 = g02;
            const float F10 = g10,        F11 = g11 + 1.0f, F12 = g12;
            const float F20 = g20,        F21 = g21,        F22 = g22 + 1.0f;

            const float det = F00 * (F11 * F22 - F12 * F21)
                            - F01 * (F10 * F22 - F12 * F20)
                            + F02 * (F10 * F21 - F11 * F20);
            const float I1 = F00*F00 + F01*F01 + F02*F02
                           + F10*F10 + F11*F11 + F12*F12
                           + F20*F20 + F21*F21 + F22*F22;
            const float lj = __logf(det);
            const float fq = 0.5f * mu * (I1 - 3.0f - 2.0f * lj)
                           + 0.5f * lam * lj * lj;
            acc = fmaf(jq[q], fq, acc);
        }
    }

    // wave-64 shuffle reduce -> per-block LDS reduce -> one atomic per block
    #pragma unroll
    for (int off = 32; off > 0; off >>= 1)
        acc += __shfl_down(acc, off, 64);
    const int lane = tid & 63;
    const int wv   = tid >> 6;
    if (lane == 0) s_wsum[wv] = acc;
    __syncthreads();
    if (tid == 0) {
        atomicAdd(out, s_wsum[0] + s_wsum[1] + s_wsum[2] + s_wsum[3]);
    }
}

extern "C" void kernel_launch(void* const* d_in, const int* in_sizes, int n_in,
                              void* d_out, int out_size, void* d_ws, size_t ws_size,
                              hipStream_t stream) {
    const float* params      = (const float*)d_in[0];
    // d_in[1] coords, d_in[2] t, d_in[4] shape_vals, d_in[7] dt — dead inputs
    const float* us          = (const float*)d_in[3];
    const float* shape_grads = (const float*)d_in[5];
    const float* jxws        = (const float*)d_in[6];
    const float* state_old   = (const float*)d_in[8];
    const int*   conns       = (const int*)d_in[9];
    float* out   = (float*)d_out;
    float4* usw  = (float4*)d_ws;   // 3.2 MB of the 256 MB scratch

    hipLaunchKernelGGL(repack_us_kernel,
                       dim3((N_NODES_C / 4 + 255) / 256), dim3(256), 0, stream,
                       us, usw);
    hipLaunchKernelGGL(fused_energy_kernel,
                       dim3((N_ELEMS_C + 255) / 256), dim3(256), 0, stream,
                       params, usw, shape_grads, jxws, conns, state_old, out);
}

// Round 5
// 127.859 us; speedup vs baseline: 1.0534x; 1.0418x over previous
//
#include <hip/hip_runtime.h>

#define N_ELEMS_C 400000
#define N_NODES_C 200000
#define STATE_N   3200000   // N_ELEMS * NQ * 1
#define N_BLOCKS  ((N_ELEMS_C + 255) / 256)   // 1563

// d_ws layout: [0, 3.2MB) = repacked us float4; [4MB, ...) = per-block partials
#define WS_PARTIALS_OFF (4 * 1024 * 1024)

// Kernel A: repack us [N_NODES][3] into [N_NODES] float4 (16B-aligned gathers).
__global__ __launch_bounds__(256) void repack_us_kernel(
    const float* __restrict__ us, float4* __restrict__ usw)
{
    const int t = blockIdx.x * 256 + threadIdx.x;   // node group [0, 50000)
    if (t < N_NODES_C / 4) {
        const float4* src = reinterpret_cast<const float4*>(us);
        const float4 a = src[3 * t + 0];
        const float4 b = src[3 * t + 1];
        const float4 c = src[3 * t + 2];
        usw[4 * t + 0] = make_float4(a.x, a.y, a.z, 0.f);
        usw[4 * t + 1] = make_float4(a.w, b.x, b.y, 0.f);
        usw[4 * t + 2] = make_float4(b.z, b.w, c.x, 0.f);
        usw[4 * t + 3] = make_float4(c.y, c.z, c.w, 0.f);
    }
}

// Kernel B: fused state passthrough + neo-Hookean energy.
// R4->R5 change: NO same-address atomic. 1563 same-dword atomicAdds cannot
// pipeline (each RMW depends on the previous value; ~60+ cyc loop latency at
// the home L2 across XCDs => ~40 us tail, matching the stuck kernel time and
// the 31% linear-decay occupancy). Blocks now store partials to d_ws
// (distinct addresses, fully pipelined); kernel C reduces them.
__global__ __launch_bounds__(256) void fused_energy_kernel(
    const float* __restrict__ params,
    const float4* __restrict__ usw,        // repacked [N_NODES] float4
    const float* __restrict__ shape_grads, // [8][8][3] = [q][n][d]
    const float* __restrict__ jxws,        // [E][8]
    const int*   __restrict__ conns,       // [E][8]
    const float* __restrict__ state_old,   // [E*8]
    float* __restrict__ partials,          // [N_BLOCKS]
    float* __restrict__ out)               // [1 + E*8]
{
    __shared__ __align__(16) float s_sgT[192];  // [q][d][n] transposed
    __shared__ float s_wsum[4];
    const int tid = threadIdx.x;
    const int b   = blockIdx.x;

    if (tid < 192) {
        const int q = tid / 24;
        const int r = tid % 24;
        const int d = r / 8;
        const int n = r % 8;
        s_sgT[tid] = shape_grads[(q * 8 + n) * 3 + d];
    }

    // ---- state passthrough (independent of s_sgT) ----
    {
        const int base4 = b * 512;
        #pragma unroll
        for (int k = 0; k < 2; ++k) {
            const int i4 = base4 + k * 256 + tid;
            if (i4 < STATE_N / 4) {
                const float4 v = reinterpret_cast<const float4*>(state_old)[i4];
                const int i = i4 * 4;
                out[1 + i + 0] = v.x;
                out[1 + i + 1] = v.y;
                out[1 + i + 2] = v.z;
                out[1 + i + 3] = v.w;
            }
        }
    }

    __syncthreads();   // s_sgT ready

    const int e = b * 256 + tid;
    float acc = 0.0f;
    if (e < N_ELEMS_C) {
        const float mu  = params[0];
        const float lam = params[1];

        const int4 c0 = reinterpret_cast<const int4*>(conns)[2 * e + 0];
        const int4 c1 = reinterpret_cast<const int4*>(conns)[2 * e + 1];
        const int ci[8] = {c0.x, c0.y, c0.z, c0.w, c1.x, c1.y, c1.z, c1.w};

        // 8 independent 16B gathers, L2-resident (3.2 MB), never line-split
        float4 uv[8];
        #pragma unroll
        for (int n = 0; n < 8; ++n) uv[n] = usw[ci[n]];

        const float4 j0 = reinterpret_cast<const float4*>(jxws)[2 * e + 0];
        const float4 j1 = reinterpret_cast<const float4*>(jxws)[2 * e + 1];
        const float jq[8] = {j0.x, j0.y, j0.z, j0.w, j1.x, j1.y, j1.z, j1.w};

        #pragma unroll
        for (int q = 0; q < 8; ++q) {
            const float4* sgq = reinterpret_cast<const float4*>(s_sgT + q * 24);
            const float4 A0 = sgq[0], A1 = sgq[1];   // d=0, n=0..7
            const float4 B0 = sgq[2], B1 = sgq[3];   // d=1
            const float4 C0 = sgq[4], C1 = sgq[5];   // d=2
            const float d0[8] = {A0.x, A0.y, A0.z, A0.w, A1.x, A1.y, A1.z, A1.w};
            const float d1[8] = {B0.x, B0.y, B0.z, B0.w, B1.x, B1.y, B1.z, B1.w};
            const float d2[8] = {C0.x, C0.y, C0.z, C0.w, C1.x, C1.y, C1.z, C1.w};

            float g00=0.f,g01=0.f,g02=0.f,g10=0.f,g11=0.f,g12=0.f,g20=0.f,g21=0.f,g22=0.f;
            #pragma unroll
            for (int n = 0; n < 8; ++n) {
                const float u0 = uv[n].x, u1 = uv[n].y, u2 = uv[n].z;
                g00 = fmaf(d0[n], u0, g00); g01 = fmaf(d1[n], u0, g01); g02 = fmaf(d2[n], u0, g02);
                g10 = fmaf(d0[n], u1, g10); g11 = fmaf(d1[n], u1, g11); g12 = fmaf(d2[n], u1, g12);
                g20 = fmaf(d0[n], u2, g20); g21 = fmaf(d1[n], u2, g21); g22 = fmaf(d2[n], u2, g22);
            }
            const float F00 = g00 + 1.0f, F01 = g01,        F02 = g02;
            const float F10 = g10,        F11 = g11 + 1.0f, F12 = g12;
            const float F20 = g20,        F21 = g21,        F22 = g22 + 1.0f;

            const float det = F00 * (F11 * F22 - F12 * F21)
                            - F01 * (F10 * F22 - F12 * F20)
                            + F02 * (F10 * F21 - F11 * F20);
            const float I1 = F00*F00 + F01*F01 + F02*F02
                           + F10*F10 + F11*F11 + F12*F12
                           + F20*F20 + F21*F21 + F22*F22;
            const float lj = __logf(det);
            const float fq = 0.5f * mu * (I1 - 3.0f - 2.0f * lj)
                           + 0.5f * lam * lj * lj;
            acc = fmaf(jq[q], fq, acc);
        }
    }

    // wave-64 shuffle reduce -> per-block LDS reduce -> ONE STORE per block
    #pragma unroll
    for (int off = 32; off > 0; off >>= 1)
        acc += __shfl_down(acc, off, 64);
    const int lane = tid & 63;
    const int wv   = tid >> 6;
    if (lane == 0) s_wsum[wv] = acc;
    __syncthreads();
    if (tid == 0) {
        partials[b] = s_wsum[0] + s_wsum[1] + s_wsum[2] + s_wsum[3];
    }
}

// Kernel C: reduce the 1563 per-block partials; single block, writes out[0].
__global__ __launch_bounds__(256) void final_reduce_kernel(
    const float* __restrict__ partials, float* __restrict__ out)
{
    __shared__ float s_wsum[4];
    const int tid = threadIdx.x;
    float acc = 0.0f;
    for (int i = tid; i < N_BLOCKS; i += 256) acc += partials[i];
    #pragma unroll
    for (int off = 32; off > 0; off >>= 1)
        acc += __shfl_down(acc, off, 64);
    const int lane = tid & 63;
    const int wv   = tid >> 6;
    if (lane == 0) s_wsum[wv] = acc;
    __syncthreads();
    if (tid == 0) {
        out[0] = s_wsum[0] + s_wsum[1] + s_wsum[2] + s_wsum[3];
    }
}

extern "C" void kernel_launch(void* const* d_in, const int* in_sizes, int n_in,
                              void* d_out, int out_size, void* d_ws, size_t ws_size,
                              hipStream_t stream) {
    const float* params      = (const float*)d_in[0];
    // d_in[1] coords, d_in[2] t, d_in[4] shape_vals, d_in[7] dt — dead inputs
    const float* us          = (const float*)d_in[3];
    const float* shape_grads = (const float*)d_in[5];
    const float* jxws        = (const float*)d_in[6];
    const float* state_old   = (const float*)d_in[8];
    const int*   conns       = (const int*)d_in[9];
    float* out      = (float*)d_out;
    float4* usw     = (float4*)d_ws;                                    // 3.2 MB
    float* partials = (float*)((char*)d_ws + WS_PARTIALS_OFF);          // 6.3 KB

    hipLaunchKernelGGL(repack_us_kernel,
                       dim3((N_NODES_C / 4 + 255) / 256), dim3(256), 0, stream,
                       us, usw);
    hipLaunchKernelGGL(fused_energy_kernel,
                       dim3(N_BLOCKS), dim3(256), 0, stream,
                       params, usw, shape_grads, jxws, conns, state_old,
                       partials, out);
    hipLaunchKernelGGL(final_reduce_kernel,
                       dim3(1), dim3(256), 0, stream,
                       partials, out);
}